// Round 1
// baseline (829.225 us; speedup 1.0000x reference)
//
#include <hip/hip_runtime.h>

#define N_NODES 20000
#define N_EDGES 320000
#define HID 128
#define OUTD 128
#define SEQ 8

typedef __attribute__((ext_vector_type(8))) short bf16x8;
typedef __attribute__((ext_vector_type(4))) float floatx4;

__device__ __forceinline__ unsigned short f2bf(float f) {
  unsigned int u = __builtin_bit_cast(unsigned int, f);
  unsigned int r = (u + 0x7fffu + ((u >> 16) & 1u)) >> 16;
  return (unsigned short)r;
}

__device__ __forceinline__ float sigf(float x) { return 1.f / (1.f + __expf(-x)); }

// ---------------- setup kernels ----------------

__global__ void k_init(float* __restrict__ deg, int* __restrict__ counts) {
  int i = blockIdx.x * 256 + threadIdx.x;
  if (i < N_NODES) { deg[i] = 1.0f; counts[i] = 0; }
}

__global__ void k_deg(const int* __restrict__ ei, const float* __restrict__ ea,
                      float* __restrict__ deg, int* __restrict__ counts) {
  int e = blockIdx.x * 256 + threadIdx.x;
  if (e >= N_EDGES) return;
  int d = ei[N_EDGES + e];
  atomicAdd(&deg[d], ea[e]);
  atomicAdd(&counts[d], 1);
}

__global__ void k_rsqrt(float* __restrict__ dinv) {
  int i = blockIdx.x * 256 + threadIdx.x;
  if (i < N_NODES) dinv[i] = rsqrtf(dinv[i]);
}

__global__ void k_scan1(const int* __restrict__ counts, int* __restrict__ incl,
                        int* __restrict__ part) {
  __shared__ int sm[256];
  int t = threadIdx.x;
  int g = blockIdx.x * 256 + t;
  int v = (g < N_NODES) ? counts[g] : 0;
  sm[t] = v;
  __syncthreads();
  for (int o = 1; o < 256; o <<= 1) {
    int add = (t >= o) ? sm[t - o] : 0;
    __syncthreads();
    sm[t] += add;
    __syncthreads();
  }
  if (g < N_NODES) incl[g] = sm[t];
  if (t == 255) part[blockIdx.x] = sm[255];
}

__global__ void k_scan2(int* __restrict__ part, int nb) {
  __shared__ int sm[128];
  int t = threadIdx.x;
  int v = (t < nb) ? part[t] : 0;
  sm[t] = v;
  __syncthreads();
  for (int o = 1; o < 128; o <<= 1) {
    int add = (t >= o) ? sm[t - o] : 0;
    __syncthreads();
    sm[t] += add;
    __syncthreads();
  }
  if (t < nb) part[t] = sm[t] - v;  // exclusive
}

__global__ void k_scan3(const int* __restrict__ incl, const int* __restrict__ counts,
                        const int* __restrict__ part, int* __restrict__ row_ptr,
                        int* __restrict__ cursor) {
  int g = blockIdx.x * 256 + threadIdx.x;
  if (g < N_NODES) {
    int start = incl[g] - counts[g] + part[blockIdx.x];
    row_ptr[g] = start;
    cursor[g] = start;
  }
  if (g == 0) row_ptr[N_NODES] = N_EDGES;
}

__global__ void k_fill(const int* __restrict__ ei, const float* __restrict__ ea,
                       const float* __restrict__ dinv, int* __restrict__ cursor,
                       int* __restrict__ csr_src, float* __restrict__ csr_w) {
  int e = blockIdx.x * 256 + threadIdx.x;
  if (e >= N_EDGES) return;
  int s = ei[e], d = ei[N_EDGES + e];
  int k = atomicAdd(&cursor[d], 1);
  csr_src[k] = s;
  csr_w[k] = dinv[s] * ea[e] * dinv[d];
}

// Transpose + bf16-convert weights: WiT[n][k] (256x256), W1T/W2T[n][k] (512x128)
__global__ void k_prep_w(const float* __restrict__ Wi, const float* __restrict__ Wc,
                         unsigned short* __restrict__ WiT,
                         unsigned short* __restrict__ W1T,
                         unsigned short* __restrict__ W2T) {
  int idx = blockIdx.x * 256 + threadIdx.x;
  if (idx >= 65536) return;
  { int n = idx >> 8, k = idx & 255; WiT[n * 256 + k] = f2bf(Wi[k * 256 + n]); }
  { int n = idx >> 7, k = idx & 127;
    W1T[n * 128 + k] = f2bf(Wc[k * 512 + n]);
    W2T[n * 128 + k] = f2bf(Wc[(k + 128) * 512 + n]); }
}

// ---------------- aggregation: one wave per node, gather via CSR ----------------
// y (bf16 as packed uint) = Agg(x): row i = x[i]*dinv[i]^2 + sum_e w_e * x[src_e]
__global__ __launch_bounds__(256) void k_agg(
    const float* __restrict__ x, unsigned int* __restrict__ y, int ystride_u,
    const float* __restrict__ dinv, const int* __restrict__ row_ptr,
    const int* __restrict__ csr_src, const float* __restrict__ csr_w) {
  int wid = (blockIdx.x * 256 + threadIdx.x) >> 6;
  int lane = threadIdx.x & 63;
  if (wid >= N_NODES) return;
  float di = dinv[wid];
  const float2* x2 = (const float2*)x;
  float2 a = x2[(size_t)wid * 64 + lane];
  float sx = a.x * di * di, sy = a.y * di * di;
  int e = row_ptr[wid], end = row_ptr[wid + 1];
  for (; e < end; ++e) {
    int s = csr_src[e];
    float w = csr_w[e];
    float2 v = x2[(size_t)s * 64 + lane];
    sx += v.x * w;
    sy += v.y * w;
  }
  y[(size_t)wid * ystride_u + lane] =
      (unsigned int)f2bf(sx) | ((unsigned int)f2bf(sy) << 16);
}

// ---------------- bf16 MFMA GEMM: C[MxN] = A[MxK] @ BT[NxK]^T + epilogue ------
// EPI 0: v += b_init[col]; elu; col<128 -> h_cur else c_cur   (N=256)
// EPI 1: Kbuf = v + b_cell[col]                                (N=512)
// EPI 2: cc = v + Kbuf                                          (N=512)
template <int EPI>
__global__ __launch_bounds__(256) void k_gemm(
    const unsigned short* __restrict__ A, int lda,
    const unsigned short* __restrict__ BT, int M, int K,
    const float* __restrict__ bias, const float* __restrict__ Kbuf,
    float* __restrict__ out0, float* __restrict__ out1) {
  __shared__ __align__(16) unsigned short sA[128 * 72];
  __shared__ __align__(16) unsigned short sB[128 * 72];
  int tid = threadIdx.x;
  int bm0 = blockIdx.x * 128;
  int bn0 = blockIdx.y * 128;
  int wave = tid >> 6, lane = tid & 63;
  int wrow = (wave >> 1) * 64, wcol = (wave & 1) * 64;
  int lr = lane & 15, lq = lane >> 4;

  floatx4 acc[4][4];
#pragma unroll
  for (int i = 0; i < 4; i++)
#pragma unroll
    for (int j = 0; j < 4; j++) acc[i][j] = (floatx4){0.f, 0.f, 0.f, 0.f};

  for (int k0 = 0; k0 < K; k0 += 64) {
    __syncthreads();
#pragma unroll
    for (int p = 0; p < 4; ++p) {
      int cch = tid + p * 256;          // 1024 chunks of 8 bf16
      int r = cch >> 3, c8 = (cch & 7) * 8;
      int grow = bm0 + r;
      float4 va = (grow < M) ? *(const float4*)(A + (size_t)grow * lda + k0 + c8)
                             : (float4){0.f, 0.f, 0.f, 0.f};
      *(float4*)(sA + r * 72 + c8) = va;
      float4 vb = *(const float4*)(BT + (size_t)(bn0 + r) * K + k0 + c8);
      *(float4*)(sB + r * 72 + c8) = vb;
    }
    __syncthreads();
#pragma unroll
    for (int ks = 0; ks < 2; ++ks) {
      int kb = ks * 32 + lq * 8;
      bf16x8 af[4], bfr[4];
#pragma unroll
      for (int mi = 0; mi < 4; mi++)
        af[mi] = *(const bf16x8*)(sA + (wrow + mi * 16 + lr) * 72 + kb);
#pragma unroll
      for (int ni = 0; ni < 4; ni++)
        bfr[ni] = *(const bf16x8*)(sB + (wcol + ni * 16 + lr) * 72 + kb);
#pragma unroll
      for (int mi = 0; mi < 4; mi++)
#pragma unroll
        for (int ni = 0; ni < 4; ni++)
          acc[mi][ni] = __builtin_amdgcn_mfma_f32_16x16x32_bf16(
              af[mi], bfr[ni], acc[mi][ni], 0, 0, 0);
    }
  }

#pragma unroll
  for (int mi = 0; mi < 4; mi++) {
#pragma unroll
    for (int r = 0; r < 4; r++) {
      int grow = bm0 + wrow + mi * 16 + lq * 4 + r;
      if (grow >= M) continue;
#pragma unroll
      for (int ni = 0; ni < 4; ni++) {
        int gcol = bn0 + wcol + ni * 16 + lr;
        float v = acc[mi][ni][r];
        if (EPI == 0) {
          v += bias[gcol];
          v = (v > 0.f) ? v : expm1f(v);
          if (gcol < 128) out0[(size_t)grow * 128 + gcol] = v;
          else out1[(size_t)grow * 128 + gcol - 128] = v;
        } else if (EPI == 1) {
          out0[(size_t)grow * 512 + gcol] = v + bias[gcol];
        } else {
          out0[(size_t)grow * 512 + gcol] = v + Kbuf[(size_t)grow * 512 + gcol];
        }
      }
    }
  }
}

// ---------------- LSTM gates ----------------
__global__ __launch_bounds__(256) void k_gates(
    const float* __restrict__ cc, float* __restrict__ c_cur,
    float* __restrict__ h_cur, float* __restrict__ out_t) {
  int idx = blockIdx.x * 256 + threadIdx.x;
  if (idx >= N_NODES * 32) return;
  int i = idx >> 5, j = (idx & 31) << 2;
  size_t b = (size_t)i * 512 + j;
  float4 gi = *(const float4*)&cc[b];
  float4 gf = *(const float4*)&cc[b + 128];
  float4 go = *(const float4*)&cc[b + 256];
  float4 gg = *(const float4*)&cc[b + 384];
  size_t hb = (size_t)i * 128 + j;
  float4 cp = *(const float4*)&c_cur[hb];
  float4 cn, hn;
  cn.x = sigf(gf.x) * cp.x + sigf(gi.x) * tanhf(gg.x);
  cn.y = sigf(gf.y) * cp.y + sigf(gi.y) * tanhf(gg.y);
  cn.z = sigf(gf.z) * cp.z + sigf(gi.z) * tanhf(gg.z);
  cn.w = sigf(gf.w) * cp.w + sigf(gi.w) * tanhf(gg.w);
  hn.x = sigf(go.x) * tanhf(cn.x);
  hn.y = sigf(go.y) * tanhf(cn.y);
  hn.z = sigf(go.z) * tanhf(cn.z);
  hn.w = sigf(go.w) * tanhf(cn.w);
  *(float4*)&c_cur[hb] = cn;
  *(float4*)&h_cur[hb] = hn;
  *(float4*)&out_t[hb] = hn;
}

// ---------------- host launcher ----------------
extern "C" void kernel_launch(void* const* d_in, const int* in_sizes, int n_in,
                              void* d_out, int out_size, void* d_ws, size_t ws_size,
                              hipStream_t stream) {
  const float* h  = (const float*)d_in[0];
  const float* c  = (const float*)d_in[1];
  const int*   ei = (const int*)d_in[2];
  const float* ea = (const float*)d_in[3];
  const float* Wi = (const float*)d_in[4];
  const float* bi = (const float*)d_in[5];
  const float* Wc = (const float*)d_in[6];
  const float* bc = (const float*)d_in[7];
  float* out = (float*)d_out;

  char* w = (char*)d_ws;
  size_t off = 0;
  auto alloc = [&](size_t bytes) {
    void* p = w + off;
    off += (bytes + 511) & ~(size_t)511;
    return p;
  };
  float* dinv          = (float*)alloc(N_NODES * 4);
  int* counts          = (int*)alloc(N_NODES * 4);
  int* cursor          = (int*)alloc(N_NODES * 4);
  int* scan_tmp        = (int*)alloc(N_NODES * 4);
  int* row_ptr         = (int*)alloc((N_NODES + 1) * 4);
  int* part            = (int*)alloc(1024 * 4);
  int* csr_src         = (int*)alloc(N_EDGES * 4);
  float* csr_w         = (float*)alloc(N_EDGES * 4);
  unsigned short* WiT  = (unsigned short*)alloc(256 * 256 * 2);
  unsigned short* W1T  = (unsigned short*)alloc(512 * 128 * 2);
  unsigned short* W2T  = (unsigned short*)alloc(512 * 128 * 2);
  unsigned short* AhAc = (unsigned short*)alloc((size_t)N_NODES * 256 * 2);
  unsigned short* Aht  = (unsigned short*)alloc((size_t)N_NODES * 128 * 2);
  float* h_cur         = (float*)alloc((size_t)N_NODES * 128 * 4);
  float* c_cur         = (float*)alloc((size_t)N_NODES * 128 * 4);
  float* Kbuf          = (float*)alloc((size_t)N_NODES * 512 * 4);
  float* cc            = (float*)alloc((size_t)N_NODES * 512 * 4);

  const int NB_N = (N_NODES + 255) / 256;   // 79
  const int NB_E = (N_EDGES + 255) / 256;   // 1250
  const int NB_AGG = N_NODES * 64 / 256;    // 5000 (one wave/node)
  const int MB = (N_NODES + 127) / 128;     // 157

  k_init<<<NB_N, 256, 0, stream>>>(dinv, counts);
  k_deg<<<NB_E, 256, 0, stream>>>(ei, ea, dinv, counts);
  k_rsqrt<<<NB_N, 256, 0, stream>>>(dinv);
  k_scan1<<<NB_N, 256, 0, stream>>>(counts, scan_tmp, part);
  k_scan2<<<1, 128, 0, stream>>>(part, NB_N);
  k_scan3<<<NB_N, 256, 0, stream>>>(scan_tmp, counts, part, row_ptr, cursor);
  k_fill<<<NB_E, 256, 0, stream>>>(ei, ea, dinv, cursor, csr_src, csr_w);
  k_prep_w<<<256, 256, 0, stream>>>(Wi, Wc, WiT, W1T, W2T);

  // Ah -> cols 0..127 of AhAc, Ac -> cols 128..255 (row stride 256 bf16)
  k_agg<<<NB_AGG, 256, 0, stream>>>(h, (unsigned int*)AhAc, 128, dinv, row_ptr,
                                    csr_src, csr_w);
  k_agg<<<NB_AGG, 256, 0, stream>>>(c, (unsigned int*)(AhAc + 128), 128, dinv,
                                    row_ptr, csr_src, csr_w);

  // states = elu([Ah|Ac] @ W_init + b_init) -> h_cur, c_cur
  k_gemm<0><<<dim3(MB, 2), 256, 0, stream>>>(AhAc, 256, WiT, N_NODES, 256, bi,
                                             nullptr, h_cur, c_cur);
  // K = Ah @ W1 + b_cell
  k_gemm<1><<<dim3(MB, 4), 256, 0, stream>>>(AhAc, 256, W1T, N_NODES, 128, bc,
                                             nullptr, Kbuf, nullptr);

  for (int t = 0; t < SEQ; ++t) {
    k_agg<<<NB_AGG, 256, 0, stream>>>(h_cur, (unsigned int*)Aht, 64, dinv,
                                      row_ptr, csr_src, csr_w);
    k_gemm<2><<<dim3(MB, 4), 256, 0, stream>>>(Aht, 128, W2T, N_NODES, 128,
                                               nullptr, Kbuf, cc, nullptr);
    k_gates<<<(N_NODES * 32 + 255) / 256, 256, 0, stream>>>(
        cc, c_cur, h_cur, out + (size_t)t * N_NODES * 128);
  }
}